// Round 2
// baseline (259.753 us; speedup 1.0000x reference)
//
#include <hip/hip_runtime.h>
#include <math.h>

// Bit-exact np-ref emulation (pinned R14, PASSING since):
//  - einsum: SOP fl(fl(w0x0)+fl(w1x1))  (no FMA)
//  - reduce: numpy BUFFERED reduce: per channel, 25 chunks of 8192; chunk =
//    64 leaves of 128-elem 8-acc blocks, balanced tree; chunks sequential.
//    var two-pass. rstd = fdiv(1,fsqrt(var+eps)). LIF fp32, each op rounded.
// R17 (data movement only; rounding order IDENTICAL):
//  - k_comb: register-resident unrolled tree; k_main: LDS-staged x, nt stores.
// R18/R19 (rounding order per element IDENTICAL):
//  - k_main: 4 consecutive (e,v) elements per thread, vec4 nontemporal
//    stores (1 KB/wave/instr vs 256 B), 3200 blocks, 1-2 b's of x in LDS.
//  - k_comb: staging widened 64->256 threads (same cb contents, same tree).
//  - R19: ext_vector_type float4 (clang vector) for the nt builtin; HIP's
//    float4 class is rejected by __builtin_nontemporal_store.
constexpr int T = 16, B = 512, C = 2, V = 25, E = 256;
constexpr int EV  = E * V;           // 6400
constexpr int BEV = B * EV;          // 3,276,800
constexpr int XT  = B * C * V;       // 25600 floats between t-slices of x
constexpr int NB  = 1600;            // 128-element blocks per channel
constexpr int CHUNKS = 25;           // 204800 / 8192
constexpr int BPC = 64;              // 128-blocks per chunk
constexpr int NROWS = 7;             // max (t,b)-rows touched by a 128-block
constexpr float NF = 204800.0f;

typedef float f32x4 __attribute__((ext_vector_type(4)));

#define WS_M32(ws) ((float*)(ws))
#define WS_R32(ws) ((float*)(ws) + E)

// ---- stage 1: per-(p,e) 128-element block-sum; bs layout [p][e] ----
template<int PASS>
__global__ void __launch_bounds__(256) k_bs(const float* __restrict__ x,
                                            const float* __restrict__ W,
                                            const float* __restrict__ ws,
                                            float* __restrict__ bs) {
    __shared__ float sx[NROWS * 50];
    int p  = blockIdx.x;             // q-block [p*128, p*128+128)
    int q0 = p * 128;
    int row_lo = q0 / 25;
    for (int i = threadIdx.x; i < NROWS * 50; i += 256) {
        int r = i / 50;
        if (row_lo + r < 8192) sx[i] = x[(row_lo + r) * 50 + (i - r * 50)];
    }
    __syncthreads();

    int e = threadIdx.x;             // one thread per channel
    float w0 = W[e * 2 + 0];
    float w1 = W[e * 2 + 1];
    float mn = (PASS == 1) ? WS_M32(ws)[e] : 0.0f;

    int v   = q0 - row_lo * 25;
    int off = v;
    float r[8];
    #pragma unroll
    for (int k = 0; k < 128; k++) {
        float y = __fadd_rn(__fmul_rn(w0, sx[off]), __fmul_rn(w1, sx[off + 25]));
        if (PASS == 1) {
            float d = __fsub_rn(y, mn);
            y = __fmul_rn(d, d);
        }
        int j = k & 7;
        r[j] = (k < 8) ? y : __fadd_rn(r[j], y);   // numpy 8-acc pattern
        v++; off++;
        if (v == 25) { v = 0; off += 25; }
    }
    bs[p * 256 + e] =
        __fadd_rn(__fadd_rn(__fadd_rn(r[0], r[1]), __fadd_rn(r[2], r[3])),
                  __fadd_rn(__fadd_rn(r[4], r[5]), __fadd_rn(r[6], r[7])));
}

// ---- stage 2: per-channel combine; register tree (no scratch) ----
template<int WHICH>
__global__ void __launch_bounds__(256) k_comb(const float* __restrict__ bs,
                                              float* __restrict__ ws) {
    __shared__ float cb[NB];
    __shared__ float csum[CHUNKS];
    int e = blockIdx.x;
    for (int i = threadIdx.x; i < NB; i += 256) cb[i] = bs[i * 256 + e];
    __syncthreads();
    if (threadIdx.x < CHUNKS) {
        int c = threadIdx.x;
        float t[BPC];                       // fully-unrolled -> VGPRs
        #pragma unroll
        for (int i = 0; i < BPC; i++) t[i] = cb[c * BPC + i];
        #pragma unroll
        for (int m = BPC / 2; m >= 1; m >>= 1) {    // balanced tree == numpy
            #pragma unroll
            for (int i = 0; i < m; i++)
                t[i] = __fadd_rn(t[2 * i], t[2 * i + 1]);
        }
        csum[c] = t[0];
    }
    __syncthreads();
    if (threadIdx.x == 0) {
        float acc = 0.0f;                   // identity init
        #pragma unroll
        for (int c = 0; c < CHUNKS; c++) acc = __fadd_rn(acc, csum[c]);
        if (WHICH == 0) {
            WS_M32(ws)[e] = __fdiv_rn(acc, NF);
        } else {
            float var = __fdiv_rn(acc, NF);
            WS_R32(ws)[e] = __fdiv_rn(1.0f, __fsqrt_rn(__fadd_rn(var, 1e-5f)));
        }
    }
}

// ---- stage 3: LIF + BN apply; 4 elems/thread, vec4 nontemporal stores ----
__global__ void __launch_bounds__(256) k_main(const float* __restrict__ x,
                                              const float* __restrict__ W,
                                              const float* __restrict__ g,
                                              const float* __restrict__ bta,
                                              const float* __restrict__ ws,
                                              float* __restrict__ out) {
    __shared__ float sx[2 * T * 50];  // up to two b's of x[b,t,c,v], 6.4 KB
    int blk = blockIdx.x;             // 3200 blocks; 1024 idx per block
    int gi0 = blk * 1024;
    int b0  = gi0 / EV;
    int nb  = ((gi0 + 1023) / EV == b0) ? 1 : 2;   // blocks straddle <=2 b's
    for (int i = threadIdx.x; i < nb * 800; i += 256) {
        int bi  = i / 800;
        int r   = i - bi * 800;
        int tt  = r / 50;
        sx[i] = x[(b0 + bi) * 50 + tt * XT + (r - tt * 50)];
    }
    __syncthreads();

    int gi  = gi0 + threadIdx.x * 4;  // 4 consecutive global (b,e,v) indices
    int b   = gi / EV;
    int rem = gi - b * EV;
    int e0  = rem / V;
    int v0  = rem - e0 * V;
    int sb  = (b - b0) * 800;
    int e1  = (e0 < E - 1) ? e0 + 1 : e0;   // channel after a v-wrap
    float w00 = W[e0 * 2], w01 = W[e0 * 2 + 1];
    float w10 = W[e1 * 2], w11 = W[e1 * 2 + 1];
    float mn0 = WS_M32(ws)[e0], mn1 = WS_M32(ws)[e1];
    float rs0 = WS_R32(ws)[e0], rs1 = WS_R32(ws)[e1];
    float ga0 = g[e0],  ga1 = g[e1];        // == 1.0f: exact no-op
    float be0 = bta[e0], be1 = bta[e1];     // == 0.0f: exact no-op

    float wA[4], wB[4], mn[4], rs[4], ga[4], be[4];
    int   vv[4];
    #pragma unroll
    for (int j = 0; j < 4; j++) {           // static indices -> registers
        int  vj = v0 + j;
        bool cr = (vj >= V);                // crossed into channel e0+1
        vv[j] = cr ? vj - V : vj;
        wA[j] = cr ? w10 : w00;  wB[j] = cr ? w11 : w01;
        mn[j] = cr ? mn1 : mn0;  rs[j] = cr ? rs1 : rs0;
        ga[j] = cr ? ga1 : ga0;  be[j] = cr ? be1 : be0;
    }

    float vm[4] = {0.0f, 0.0f, 0.0f, 0.0f};
    #pragma unroll
    for (int t = 0; t < T; t++) {
        f32x4 o;
        #pragma unroll
        for (int j = 0; j < 4; j++) {
            float x0 = sx[sb + t * 50 + vv[j]];
            float x1 = sx[sb + t * 50 + 25 + vv[j]];
            float y = __fadd_rn(__fmul_rn(wA[j], x0), __fmul_rn(wB[j], x1));
            y = __fmul_rn(__fsub_rn(y, mn[j]), rs[j]);      // (y-mean)*rstd
            y = __fadd_rn(__fmul_rn(y, ga[j]), be[j]);      // *gamma+beta
            float d = __fmul_rn(__fsub_rn(y, vm[j]), 0.5f); // (y-v)/2.0
            vm[j] = __fadd_rn(vm[j], d);                    // v += ...
            bool sp = (vm[j] >= 1.0f);
            o[j] = sp ? 1.0f : 0.0f;
            if (sp) vm[j] = 0.0f;                           // hard reset
        }
        __builtin_nontemporal_store(o,
            reinterpret_cast<f32x4*>(&out[(size_t)t * BEV + gi]));
    }
}

extern "C" void kernel_launch(void* const* d_in, const int* in_sizes, int n_in,
                              void* d_out, int out_size, void* d_ws, size_t ws_size,
                              hipStream_t stream) {
    (void)in_sizes; (void)n_in; (void)out_size; (void)ws_size;
    const float* x  = (const float*)d_in[0];
    const float* W  = (const float*)d_in[1];
    const float* g  = (const float*)d_in[2];
    const float* bb = (const float*)d_in[3];
    float* ws = (float*)d_ws;        // 2 KB: mean[256], rstd[256]
    float* bs = (float*)d_out;       // scratch 1.6 MB; k_main overwrites all

    k_bs<0><<<NB, 256, 0, stream>>>(x, W, ws, bs);
    k_comb<0><<<E, 256, 0, stream>>>(bs, ws);
    k_bs<1><<<NB, 256, 0, stream>>>(x, W, ws, bs);
    k_comb<1><<<E, 256, 0, stream>>>(bs, ws);
    k_main<<<BEV / 1024, 256, 0, stream>>>(x, W, g, bb, ws, (float*)d_out);
}